// Round 12
// baseline (393.139 us; speedup 1.0000x reference)
//
#include <hip/hip_runtime.h>
#include <stdint.h>

#define N_  8
#define CK  128
#define CV  512
#define HW  900     // 30*30 queries
#define M_  7200    // 8*30*30 memory slots
#define QK_SCALE 0.08838834764831845f  // 1/sqrt(128)

typedef __attribute__((ext_vector_type(8))) short  short8;
typedef __attribute__((ext_vector_type(4))) float  floatx4;
typedef __attribute__((ext_vector_type(4))) unsigned int   uintx4;
typedef __attribute__((ext_vector_type(4))) unsigned short ushortx4;

__device__ __forceinline__ uint16_t f32_to_bf16(float x) {
    union { float f; uint32_t u; } v; v.f = x;
    return (uint16_t)((v.u + 0x7FFFu + ((v.u >> 16) & 1u)) >> 16);
}

// Direct HBM -> LDS DMA, 16 B per lane. LDS dest is wave-uniform base
// (hardware adds lane*16B); global src is per-lane.
__device__ __forceinline__ void gload_lds16(const uint16_t* g, short* l) {
    __builtin_amdgcn_global_load_lds(
        (const __attribute__((address_space(1))) void*)g,
        (__attribute__((address_space(3))) void*)l,
        16, 0, 0);
}

// counted-vmcnt wait: loads stay in flight across barriers (T4)
#define WAITV(n) asm volatile("s_waitcnt vmcnt(" #n ")" ::: "memory")
// full fence barrier: sched_barrier on BOTH sides so no memory op (incl.
// global_load_lds) migrates across the s_barrier (m152 race class).
#define BARRIER() do { __builtin_amdgcn_sched_barrier(0); \
                       __builtin_amdgcn_s_barrier(); \
                       __builtin_amdgcn_sched_barrier(0); } while (0)

// ---------------------------------------------------------------- fused prep (r8-fixed, passing):
// [0,928)        transpose qkey -> qkT   (29 x 4 x 8 tiles, L=900)
// [928,8128)     transpose mkey -> mkT   (225 x 4 x 8 tiles, L=7200)
// [8128,11728)   copy q_val -> out first half (3600 blocks: N*CV*HW/4/256)
// [11728,11953)  zero dsum (225 blocks)
__device__ __forceinline__ void trans_body(const float* __restrict__ in,
                                           uint16_t* __restrict__ outp, int L,
                                           int bx, int by, int bz, int tid) {
    __shared__ float tile[32][33];
    const int tx = tid & 31;
    const int ty = tid >> 5;
    const int l0 = bx * 32;
    const int c0 = by * 32;
    const float* src = in + (size_t)bz * CK * L;
    uint16_t* dst = outp + (size_t)bz * L * CK;
#pragma unroll
    for (int p = 0; p < 4; p++) {
        int c = c0 + p * 8 + ty;
        int l = l0 + tx;
        float v = 0.f;
        if (l < L) v = src[(size_t)c * L + l];
        tile[p * 8 + ty][tx] = v;
    }
    __syncthreads();
#pragma unroll
    for (int p = 0; p < 4; p++) {
        int l = l0 + p * 8 + ty;
        int c = c0 + tx;
        if (l < L) dst[(size_t)l * CK + c] = f32_to_bf16(tile[tx][p * 8 + ty]);
    }
}

__global__ __launch_bounds__(256) void k_prep(
    const float* __restrict__ qkey, const float* __restrict__ mkey,
    const float* __restrict__ qval, float* __restrict__ out,
    uint16_t* __restrict__ qkT, uint16_t* __restrict__ mkT,
    float* __restrict__ dsum)
{
    const int b = blockIdx.x;
    const int tid = threadIdx.x;
    if (b < 928) {
        trans_body(qkey, qkT, HW, b % 29, (b / 29) & 3, b / 116, tid);
    } else if (b < 8128) {
        const int bb = b - 928;
        trans_body(mkey, mkT, M_, bb % 225, (bb / 225) & 3, bb / 900, tid);
    } else if (b < 11728) {
        const int bb = b - 8128;
        unsigned i = (unsigned)bb * 256 + tid;    // 0..921599
        unsigned e = i * 4u;                      // float index, < 3,686,400
        unsigned n = e / (CV * HW);
        unsigned off = e - n * (CV * HW);
        *(floatx4*)&out[(size_t)n * (2 * CV * HW) + off] = *(const floatx4*)&qval[e];
    } else {
        const int bb = b - 11728;
        int i = bb * 256 + tid;
        if (i < N_ * M_) dsum[i] = 0.f;
    }
}

// ---------------------------------------------------------------- K1: aff = qkT mkT^T, exp, colsum
// Ring-3 depth-2 counted-vmcnt pipeline (BK=32) — r10 verbatim (passing x2).
#define K1_TS 144   // C-tile stride (shorts)

__global__ __launch_bounds__(256) void k1_gemm_exp(
    const uint16_t* __restrict__ qkT,  // [N][HW][CK] bf16 (A: rows q, k=c)
    const uint16_t* __restrict__ mkT,  // [N][M][CK] bf16  (B: rows m, k=c)
    uint16_t* __restrict__ E,          // [N][HW][M] bf16 = exp(aff*scale)
    float* __restrict__ dsum)          // [N][M]
{
    __shared__ __align__(16) short smem[24576];   // 3 bufs x (A 4096 + B 4096); C-tile 18432 fits
    __shared__ float colsum[128];

    // XCD swizzle: 3648 blocks, 456/XCD = exactly one n-plane per XCD.
    const int bid = blockIdx.x + 57 * (blockIdx.y + 8 * blockIdx.z);
    const int swz = (bid & 7) * 456 + (bid >> 3);
    const int mb   = swz % 57;
    const int rest = swz / 57;
    const int m0 = mb * 128;
    const int q0 = (rest & 7) * 128;
    const int n  = rest >> 3;
    const int tid = threadIdx.x;

    if (tid < 128) colsum[tid] = 0.f;

    const int lane = tid & 63;
    const int wid  = tid >> 6;
    const int wq   = (wid >> 1) << 6;
    const int wm   = (wid & 1) << 6;
    const int fr   = lane & 15;
    const int quad = lane >> 4;

    const int ca = wid * 2;
    const int rr = lane >> 2;        // row within chunk 0..15
    const int cc = (lane & 3) * 8;   // col (shorts), 16B aligned

    const uint16_t* Ab = qkT + (size_t)n * HW * CK;
    const uint16_t* Bb = mkT + (size_t)n * M_ * CK;
    const uint16_t* A0p = Ab + (size_t)(q0 + ca * 16 + rr) * CK + cc;
    const uint16_t* A1p = A0p + 16 * CK;
    const uint16_t* B0p = Bb + (size_t)(m0 + ca * 16 + rr) * CK + cc;
    const uint16_t* B1p = B0p + 16 * CK;

    floatx4 acc[4][4];
#pragma unroll
    for (int a = 0; a < 4; a++)
#pragma unroll
        for (int b = 0; b < 4; b++) acc[a][b] = (floatx4){0.f, 0.f, 0.f, 0.f};

#define K1_STAGE(buf, ko) do { \
    short* dA = smem + (buf) * 8192 + ca * 512; \
    short* dB = dA + 4096; \
    gload_lds16(A0p + (ko), dA); \
    gload_lds16(A1p + (ko), dA + 512); \
    gload_lds16(B0p + (ko), dB); \
    gload_lds16(B1p + (ko), dB + 512); \
} while (0)

#define K1_COMPUTE(buf) do { \
    const short* bA = smem + (buf) * 8192; \
    const short* bB = bA + 4096; \
    const int k0 = quad * 8; \
    short8 af[4], bfr[4]; \
    _Pragma("unroll") \
    for (int t = 0; t < 4; t++) \
        af[t] = *(const short8*)&bA[(wq + t * 16 + fr) * 32 + k0]; \
    _Pragma("unroll") \
    for (int t = 0; t < 4; t++) \
        bfr[t] = *(const short8*)&bB[(wm + t * 16 + fr) * 32 + k0]; \
    _Pragma("unroll") \
    for (int tq = 0; tq < 4; tq++) \
        _Pragma("unroll") \
        for (int tm = 0; tm < 4; tm++) \
            acc[tq][tm] = __builtin_amdgcn_mfma_f32_16x16x32_bf16( \
                af[tq], bfr[tm], acc[tq][tm], 0, 0, 0); \
} while (0)

    // ring-3 depth-2 over 4 K-steps (tiles 0..3; tile->buf = tile%3)
    K1_STAGE(0, 0); K1_STAGE(1, 32);
    WAITV(4); BARRIER(); K1_STAGE(2, 64); K1_COMPUTE(0);   // t=0
    WAITV(4); BARRIER(); K1_STAGE(0, 96); K1_COMPUTE(1);   // t=1 (tile3->buf0)
    WAITV(4); BARRIER(); K1_COMPUTE(2);                    // t=2
    WAITV(0); BARRIER(); K1_COMPUTE(0);                    // t=3 (tile3 in buf0)

    // ---- epilogue phase A: exp -> LDS C-tile (stride 144), colsum
    __syncthreads();   // all frag reads done; smem reusable as C-tile
    float cs[4] = {0.f, 0.f, 0.f, 0.f};
#pragma unroll
    for (int tq = 0; tq < 4; tq++) {
#pragma unroll
        for (int tm = 0; tm < 4; tm++) {
            const int col = wm + tm * 16 + fr;
#pragma unroll
            for (int i = 0; i < 4; i++) {
                const int row = wq + tq * 16 + quad * 4 + i;
                float e = __expf(acc[tq][tm][i] * QK_SCALE);
                if (q0 + row < HW) cs[tm] += e;   // guard: padded q-rows must not pollute colsum
                smem[row * K1_TS + col] = (short)f32_to_bf16(e);
            }
        }
    }
#pragma unroll
    for (int tm = 0; tm < 4; tm++) {
        float s = cs[tm];
        s += __shfl_xor(s, 16, 64);
        s += __shfl_xor(s, 32, 64);
        if (quad == 0) atomicAdd(&colsum[wm + tm * 16 + fr], s);
    }
    __syncthreads();   // C-tile complete + colsum complete

    // ---- epilogue phase B: coalesced uint4 E-writes (8 per thread)
    uint16_t* En = E + (size_t)n * HW * M_;
#pragma unroll
    for (int j = 0; j < 8; j++) {
        int idx = tid + j * 256;       // 0..2047 = 128 rows x 16 uint4
        int r   = idx >> 4;
        int c8  = (idx & 15) * 8;      // short offset in row
        if (q0 + r < HW && m0 + c8 + 8 <= M_) {
            uintx4 v = *(const uintx4*)&smem[r * K1_TS + c8];
            *(uintx4*)&En[(size_t)(q0 + r) * M_ + m0 + c8] = v;
        }
    }
    if (tid < 128) {
        const int gm = m0 + tid;
        if (gm < M_) atomicAdd(&dsum[(size_t)n * M_ + gm], colsum[tid]);
    }
#undef K1_STAGE
#undef K1_COMPUTE
}

// ---------------------------------------------------------------- mvs = bf16(mv / dsum[m])
__global__ __launch_bounds__(256) void k_mvs(
    const float* __restrict__ mval,   // [N][CV][M]
    const float* __restrict__ dsum,   // [N][M]
    uint16_t* __restrict__ mvs)       // [N][CV][M]
{
    unsigned i = blockIdx.x * 256 + threadIdx.x;
    unsigned base = i * 4u;
    unsigned n = base / (unsigned)(CV * M_);
    unsigned m = base % (unsigned)M_;
    floatx4 v = *(const floatx4*)&mval[base];
    floatx4 d = *(const floatx4*)&dsum[n * (unsigned)M_ + m];
    ushortx4 o;
    o[0] = f32_to_bf16(v[0] * (1.0f / d[0]));
    o[1] = f32_to_bf16(v[1] * (1.0f / d[1]));
    o[2] = f32_to_bf16(v[2] * (1.0f / d[2]));
    o[3] = f32_to_bf16(v[3] * (1.0f / d[3]));
    *(ushortx4*)&mvs[base] = o;
}

// ---------------------------------------------------------------- K2: 128c x 128q block, 2 waves, 64x128 wave tiles
// r11 post-mortem: wall = max-CU LDS bytes at ~35 B/cyc effective; r11's
// 384-block grid left the wall-CU at 10.8 MB (same as r10) due to imbalance.
// Fix: 128c x 128q blocks (2 waves, each 64c x 128q) -> ring-3 x 16KB = 48KB
// LDS -> 3 blocks/CU; grid 4c x 8q x 24nz = 768 = EXACTLY 3/CU. Max-CU
// bytes: 3 x 75 x 40KB = 9.0 MB (was 10.8). Same 0.375 KB-read/MFMA
// geometry as r11. Ledger (8 gloads/wave/stage): prologue 2 stages = 16
// out; WAITV(8) drains tile t; stage t+2 -> buf (t+2)%3 (WAR-safe, same
// invariant as r10/r11). Tail: WAITV(8)/WAITV(0).
#define K2_SPLITS 3
#define K2_BK 32
#define K2_STEPS 75   // 2400 / 32

__global__ __launch_bounds__(128, 2) void k2_128(
    const uint16_t* __restrict__ mvs,  // [N][CV][M] bf16 (already / dsum)
    const uint16_t* __restrict__ E,    // [N][HW][M] bf16
    float* __restrict__ partials)      // [3][N][CV][HW]
{
    __shared__ __align__(16) short lds2[24576];   // 3 bufs x (A 4096 + B 4096 shorts)

    // XCD swizzle: 768 blocks, 96/XCD (bijective); q0 fastest so the 8
    // q-blocks sharing an A-panel (same c0,nz) are adjacent on one XCD.
    const int bid = blockIdx.x + 8 * (blockIdx.y + 4 * blockIdx.z);
    const int swz = (bid & 7) * 96 + (bid >> 3);
    const int q0 = (swz & 7) << 7;           // 0..896
    const int c0 = ((swz >> 3) & 3) << 7;    // 0,128,256,384
    const int nz = swz >> 5;                 // 0..23
    const int n     = nz / K2_SPLITS;
    const int split = nz - n * K2_SPLITS;
    const int tid = threadIdx.x;             // 0..127

    const int lane = tid & 63;
    const int wid  = tid >> 6;       // 0..1; wave owns c-range [wid*64, wid*64+64)
    const int fr   = lane & 15;
    const int quad = lane >> 4;

    // staging: A = [128c][32m] (8 chunks of 16 rows), wave owns 4 chunks
    // (rows 64*wid..64*wid+63); B = [128q][32m] same split. Per-lane src:
    // row rr (lane>>2) within chunk, col cc.
    const int rr = lane >> 2;
    const int cc = (lane & 3) * 8;

    const uint16_t* Asrc = mvs + (size_t)(n * CV + c0) * M_ + split * 2400;
    const uint16_t* Bsrc = E + (size_t)n * HW * M_ + split * 2400;
    const uint16_t* Ap0 = Asrc + (size_t)(wid * 64 + rr) * M_ + cc;        // chunk j: +j*16*M_
    // B OOB (q0=896 block: rows to 1023): reads stay inside workspace
    // (<105.5 MB < 207 MB); poisoned acc cols never written (gq<HW guard).
    const uint16_t* Bp0 = Bsrc + (size_t)(q0 + wid * 64 + rr) * M_ + cc;   // chunk j: +j*16*M_

    floatx4 acc[4][8];
#pragma unroll
    for (int a = 0; a < 4; a++)
#pragma unroll
        for (int b = 0; b < 8; b++) acc[a][b] = (floatx4){0.f, 0.f, 0.f, 0.f};

#define K2_STAGE(buf, mo) do { \
    short* dA = lds2 + (buf) * 8192 + wid * 2048; \
    short* dB = lds2 + (buf) * 8192 + 4096 + wid * 2048; \
    gload_lds16(Ap0 + (mo), dA); \
    gload_lds16(Ap0 + (size_t)16 * M_ + (mo), dA + 512); \
    gload_lds16(Ap0 + (size_t)32 * M_ + (mo), dA + 1024); \
    gload_lds16(Ap0 + (size_t)48 * M_ + (mo), dA + 1536); \
    gload_lds16(Bp0 + (mo), dB); \
    gload_lds16(Bp0 + (size_t)16 * M_ + (mo), dB + 512); \
    gload_lds16(Bp0 + (size_t)32 * M_ + (mo), dB + 1024); \
    gload_lds16(Bp0 + (size_t)48 * M_ + (mo), dB + 1536); \
} while (0)

#define K2_COMPUTE(buf) do { \
    const short* bA = lds2 + (buf) * 8192; \
    const short* bB = bA + 4096; \
    const int k0 = quad * 8; \
    short8 af[4], bfr[8]; \
    _Pragma("unroll") \
    for (int t = 0; t < 4; t++) \
        af[t] = *(const short8*)&bA[(wid * 64 + t * 16 + fr) * 32 + k0]; \
    _Pragma("unroll") \
    for (int t = 0; t < 8; t++) \
        bfr[t] = *(const short8*)&bB[(t * 16 + fr) * 32 + k0]; \
    _Pragma("unroll") \
    for (int tc = 0; tc < 4; tc++) \
        _Pragma("unroll") \
        for (int tq = 0; tq < 8; tq++) \
            acc[tc][tq] = __builtin_amdgcn_mfma_f32_16x16x32_bf16( \
                af[tc], bfr[tq], acc[tc][tq], 0, 0, 0); \
} while (0)

    // ring-3 depth-2 over 75 tiles (tile->buf = tile%3)
    K2_STAGE(0, 0);
    K2_STAGE(1, K2_BK);
    for (int s = 0; s < 24; s++) {                // t = 3s..3s+2 (0..71)
        int mo = (3 * s + 2) * K2_BK;
        WAITV(8); BARRIER();
        K2_STAGE(2, mo); K2_COMPUTE(0);           // t=3s:   stage tile t+2 -> buf2
        WAITV(8); BARRIER();
        K2_STAGE(0, mo + K2_BK); K2_COMPUTE(1);   // t=3s+1: -> buf0
        WAITV(8); BARRIER();
        K2_STAGE(1, mo + 2 * K2_BK); K2_COMPUTE(2); // t=3s+2: -> buf1
    }
    // t=72: stage tile 74 -> buf2; compute tile 72 (buf0)
    WAITV(8); BARRIER();
    K2_STAGE(2, 74 * K2_BK); K2_COMPUTE(0);
    // t=73: compute tile 73 (buf1)
    WAITV(8); BARRIER();
    K2_COMPUTE(1);
    // t=74: compute tile 74 (buf2)
    WAITV(0); BARRIER();
    K2_COMPUTE(2);

    // epilogue: store partials. gc = c0 + wid*64 + tc*16 + quad*4 + i;
    // gq = q0 + tq*16 + fr (verified MFMA C/D mapping, r4/r10/r11).
    float* P = partials + ((size_t)split * N_ + n) * CV * HW;
#pragma unroll
    for (int tc = 0; tc < 4; tc++) {
#pragma unroll
        for (int tq = 0; tq < 8; tq++) {
            const int gq = q0 + tq * 16 + fr;
            if (gq < HW) {
#pragma unroll
                for (int i = 0; i < 4; i++) {
                    const int gc = c0 + wid * 64 + tc * 16 + quad * 4 + i;
                    P[(size_t)gc * HW + gq] = acc[tc][tq][i];
                }
            }
        }
    }
#undef K2_STAGE
#undef K2_COMPUTE
}

// ---------------------------------------------------------------- reduce 3 partials -> out mapped half
__global__ __launch_bounds__(256) void k_reduce3(const float* __restrict__ partials,
                                                 float* __restrict__ out) {
    unsigned i = blockIdx.x * 256 + threadIdx.x;
    unsigned e = i * 4u;
    unsigned n = e / (CV * HW);
    unsigned off = e - n * (CV * HW);
    const size_t stride = (size_t)N_ * CV * HW;
    const float* p = partials + (size_t)n * CV * HW + off;
    floatx4 a = *(const floatx4*)&p[0];
    floatx4 b = *(const floatx4*)&p[stride];
    floatx4 c = *(const floatx4*)&p[2 * stride];
    floatx4 s = a + b + c;
    *(floatx4*)&out[(size_t)n * (2 * CV * HW) + CV * HW + off] = s;
}

// ----------------------------------------------------------------
extern "C" void kernel_launch(void* const* d_in, const int* in_sizes, int n_in,
                              void* d_out, int out_size, void* d_ws, size_t ws_size,
                              hipStream_t stream) {
    const float* qkey = (const float*)d_in[0];  // [8][128][900]
    const float* qval = (const float*)d_in[1];  // [8][512][900]
    const float* mkey = (const float*)d_in[2];  // [8][128][7200]
    const float* mval = (const float*)d_in[3];  // [8][512][7200]
    float* out = (float*)d_out;                 // [8][1024][900]

    char* ws = (char*)d_ws;
    // E 103,680,000 | dsum 230,400 | (gap) | mvs 58,982,400 | partials 44,236,800
    // qkT/mkT alias partials (dead before k2_128 writes partials).
    uint16_t* E        = (uint16_t*)ws;
    float*    dsum     = (float*)(ws + 103680000);
    uint16_t* mvs      = (uint16_t*)(ws + 104140800);
    float*    partials = (float*)(ws + 163123200);
    uint16_t* qkT      = (uint16_t*)(ws + 163123200);
    uint16_t* mkT      = (uint16_t*)(ws + 163123200 + 1843200);

    (void)in_sizes; (void)n_in; (void)out_size; (void)ws_size;

    k_prep<<<dim3(11953), 256, 0, stream>>>(qkey, mkey, qval, out, qkT, mkT, dsum);
    k1_gemm_exp<<<dim3(57, 8, N_), 256, 0, stream>>>(qkT, mkT, E, dsum);
    k_mvs<<<dim3((N_ * CV * M_) / 4 / 256), 256, 0, stream>>>(mval, dsum, mvs);
    k2_128<<<dim3(8, 4, 24), 128, 0, stream>>>(mvs, E, partials);
    k_reduce3<<<dim3((N_ * CV * HW) / 4 / 256), 256, 0, stream>>>(partials, out);
}